// Round 10
// baseline (94.581 us; speedup 1.0000x reference)
//
#include <hip/hip_runtime.h>
#include <hip/hip_bf16.h>

#define SQ 1024
#define HH 16
#define DK 4
#define EE 64

// R10 PROBE: compute phases internally repeated (qattn x8, proj x16) so our
// dispatches exceed the harness's 38us fill kernels and appear in rocprof
// top-5. Idempotent: each rep rewrites identical y/out. Per-pass cost =
// row_dur/reps. This finally separates kernel time from launch overhead and
// shows which pipe (VALU vs trans vs MFMA vs LDS) is saturated.

using short8 = __attribute__((ext_vector_type(8))) short;
using f32x4  = __attribute__((ext_vector_type(4))) float;
using us4    = __attribute__((ext_vector_type(4))) unsigned short;
using us8    = __attribute__((ext_vector_type(8))) unsigned short;
using u32x4  = __attribute__((ext_vector_type(4))) unsigned;

static __device__ inline unsigned short f2bf(float f) {
  return __builtin_bit_cast(unsigned short, __float2bfloat16(f));
}

static __device__ inline unsigned trunc_pk_bf16(float lo, float hi) {
  return __builtin_amdgcn_perm(__builtin_bit_cast(unsigned, hi),
                               __builtin_bit_cast(unsigned, lo),
                               0x07060302u);
}

__global__ __launch_bounds__(512) void qattn_mfma(
    const float* __restrict__ x, const float* __restrict__ theta,
    float* __restrict__ y) {
  const int tid = threadIdx.x;
  const int quarter = blockIdx.x & 3;
  const int bh = blockIdx.x >> 2;
  const int hd = bh & (HH - 1);
  const int b = bh >> 4;

  __shared__ __align__(16) unsigned short afrag[32][16][8];   // 8 KB
  __shared__ __align__(16) unsigned short vfrag[32][4][5][8]; // 10 KB
  __shared__ __align__(16) unsigned short qfrag[256][4];      // 2 KB
  __shared__ __align__(16) unsigned short zslot[8];

  const float4 th = *reinterpret_cast<const float4*>(theta);
  const float ct[4] = {__cosf(th.x), __cosf(th.y), __cosf(th.z), __cosf(th.w)};
  const float sc = 0.5f * 1.4426950408889634f;
  const int q_lo = quarter * 256;

  if (tid < 8) zslot[tid] = 0;
#pragma unroll
  for (int k = 0; k < 2; ++k) {
    const int e = tid + k * 512;
    vfrag[e >> 5][(e >> 3) & 3][4][e & 7] = 0x3F80;
  }

  const float* xb = x + ((size_t)b * SQ) * EE + hd * DK;
#pragma unroll
  for (int k = 0; k < 2; ++k) {
    const int t = tid + k * 512;
    const float4 v = *reinterpret_cast<const float4*>(xb + (size_t)t * EE);
    const float p[4] = {__cosf(v.x) * ct[0], __cosf(v.y) * ct[1],
                        __cosf(v.z) * ct[2], __cosf(v.w) * ct[3]};
    unsigned short pb[4], qb[4];
#pragma unroll
    for (int d = 0; d < 4; ++d) {
      pb[d] = f2bf(p[d]);
      qb[d] = f2bf(p[d] * sc);
    }
    const int c = t >> 5, tl = t & 31, hq = tl >> 3, j = tl & 7;
    *reinterpret_cast<us4*>(&afrag[c][4 * hq + (j & 3)][(j >= 4) ? 4 : 0]) =
        (us4){pb[0], pb[1], pb[2], pb[3]};
#pragma unroll
    for (int nn = 0; nn < 4; ++nn) vfrag[c][hq][nn][j] = pb[nn];
    const int ql = t - q_lo;
    if ((unsigned)ql < 256u)
      *reinterpret_cast<us4*>(&qfrag[ql][0]) = (us4){qb[0], qb[1], qb[2], qb[3]};
  }
  __syncthreads();

  const int lane = tid & 63;
  const int wid = tid >> 6;
  const int n = lane & 15, hg = lane >> 4;

  short8 qf0 = {0, 0, 0, 0, 0, 0, 0, 0}, qf1 = qf0;
  {
    const unsigned short* qa =
        (lane < 16) ? &qfrag[wid * 32 + n][0] : &zslot[0];
    const unsigned short* qb2 =
        (lane < 16) ? &qfrag[wid * 32 + 16 + n][0] : &zslot[0];
    const us4 ta = *reinterpret_cast<const us4*>(qa);
    const us4 tb = *reinterpret_cast<const us4*>(qb2);
#pragma unroll
    for (int i = 0; i < 4; ++i) { qf0[i] = (short)ta[i]; qf1[i] = (short)tb[i]; }
  }

  const unsigned short* aptr = (lane < 16) ? &afrag[0][n][0] : &zslot[0];
  const int astep = (lane < 16) ? 128 : 0;
  const unsigned short* vptr = (n <= 4) ? &vfrag[0][hg][n][0] : &zslot[0];
  const int vstep = (n <= 4) ? 160 : 0;

  const float csh = 0.0056245491938781f;

  // ===== repeated compute phase (x8) =====
#pragma unroll 1
  for (int rep = 0; rep < 8; ++rep) {
    asm volatile("" ::: "memory");  // defeat CSE across reps
    f32x4 acc0 = {0.f, 0.f, 0.f, 0.f}, acc1 = acc0;
    const f32x4 cc = {csh, csh, csh, csh};

#pragma unroll 2
    for (int c = 0; c < 32; ++c) {
      const us8 av = *reinterpret_cast<const us8*>(aptr + c * astep);
      const short8 A1 = {(short)av[0], (short)av[1], (short)av[2], (short)av[3],
                         0, 0, 0, 0};
      const short8 A2 = {(short)av[4], (short)av[5], (short)av[6], (short)av[7],
                         0, 0, 0, 0};
      const f32x4 s1a = __builtin_amdgcn_mfma_f32_16x16x32_bf16(A1, qf0, cc, 0, 0, 0);
      const f32x4 s2a = __builtin_amdgcn_mfma_f32_16x16x32_bf16(A2, qf0, cc, 0, 0, 0);
      const f32x4 s1b = __builtin_amdgcn_mfma_f32_16x16x32_bf16(A1, qf1, cc, 0, 0, 0);
      const f32x4 s2b = __builtin_amdgcn_mfma_f32_16x16x32_bf16(A2, qf1, cc, 0, 0, 0);

      u32x4 p0, p1;
      p0[0] = trunc_pk_bf16(__builtin_amdgcn_exp2f(s1a[0]),
                            __builtin_amdgcn_exp2f(s1a[1]));
      p0[1] = trunc_pk_bf16(__builtin_amdgcn_exp2f(s1a[2]),
                            __builtin_amdgcn_exp2f(s1a[3]));
      p0[2] = trunc_pk_bf16(__builtin_amdgcn_exp2f(s2a[0]),
                            __builtin_amdgcn_exp2f(s2a[1]));
      p0[3] = trunc_pk_bf16(__builtin_amdgcn_exp2f(s2a[2]),
                            __builtin_amdgcn_exp2f(s2a[3]));
      p1[0] = trunc_pk_bf16(__builtin_amdgcn_exp2f(s1b[0]),
                            __builtin_amdgcn_exp2f(s1b[1]));
      p1[1] = trunc_pk_bf16(__builtin_amdgcn_exp2f(s1b[2]),
                            __builtin_amdgcn_exp2f(s1b[3]));
      p1[2] = trunc_pk_bf16(__builtin_amdgcn_exp2f(s2b[0]),
                            __builtin_amdgcn_exp2f(s2b[1]));
      p1[3] = trunc_pk_bf16(__builtin_amdgcn_exp2f(s2b[2]),
                            __builtin_amdgcn_exp2f(s2b[3]));
      const short8 PA0 = __builtin_bit_cast(short8, p0);
      const short8 PA1 = __builtin_bit_cast(short8, p1);

      const us8 vv = *reinterpret_cast<const us8*>(vptr + c * vstep);
      const short8 VB = __builtin_bit_cast(short8, vv);
      acc0 = __builtin_amdgcn_mfma_f32_16x16x32_bf16(PA0, VB, acc0, 0, 0, 0);
      acc1 = __builtin_amdgcn_mfma_f32_16x16x32_bf16(PA1, VB, acc1, 0, 0, 0);
    }

#pragma unroll
    for (int half = 0; half < 2; ++half) {
      const f32x4 acc = half ? acc1 : acc0;
      const int qbase = q_lo + wid * 32 + half * 16;
#pragma unroll
      for (int r = 0; r < 4; ++r) {
        const float den = __shfl(acc[r], (lane & 48) | 4, 64);
        const float val = acc[r] * (1.0f / den);
        if (n < 4) {
          y[((size_t)(b * SQ + qbase + 4 * hg + r)) * EE + hd * DK + n] = val;
        }
      }
    }
  }
}

__global__ __launch_bounds__(256) void proj_kernel(
    const float* __restrict__ y, const float* __restrict__ W,
    const float* __restrict__ bias, float* __restrict__ out) {
  const int tid = threadIdx.x;
  __shared__ float Wt[EE][68];
  __shared__ float yt[16][68];

  const float4* W4 = reinterpret_cast<const float4*>(W);
#pragma unroll
  for (int k = 0; k < 4; ++k) {
    const int i4 = tid + k * 256;
    const float4 w = W4[i4];
    const int e = i4 >> 4;
    const int j0 = (i4 & 15) * 4;
    Wt[j0 + 0][e] = w.x; Wt[j0 + 1][e] = w.y;
    Wt[j0 + 2][e] = w.z; Wt[j0 + 3][e] = w.w;
  }
  const size_t tok0 = (size_t)blockIdx.x * 16;
  {
    const float4 v = reinterpret_cast<const float4*>(y + tok0 * EE)[tid];
    *reinterpret_cast<float4*>(&yt[tid >> 4][(tid & 15) * 4]) = v;
  }
  __syncthreads();

  const int t = tid >> 4;
  const int eg = tid & 15;
  const int e0 = eg * 4;

  // ===== repeated compute phase (x16) =====
#pragma unroll 1
  for (int rep = 0; rep < 16; ++rep) {
    asm volatile("" ::: "memory");
    f32x4 acc = *reinterpret_cast<const f32x4*>(bias + e0);
#pragma unroll
    for (int jq = 0; jq < 16; ++jq) {
      const f32x4 yv = *reinterpret_cast<const f32x4*>(&yt[t][jq * 4]);
      const f32x4 w0 = *reinterpret_cast<const f32x4*>(&Wt[jq * 4 + 0][e0]);
      const f32x4 w1 = *reinterpret_cast<const f32x4*>(&Wt[jq * 4 + 1][e0]);
      const f32x4 w2 = *reinterpret_cast<const f32x4*>(&Wt[jq * 4 + 2][e0]);
      const f32x4 w3 = *reinterpret_cast<const f32x4*>(&Wt[jq * 4 + 3][e0]);
      acc += yv[0] * w0 + yv[1] * w1 + yv[2] * w2 + yv[3] * w3;
    }
    *reinterpret_cast<f32x4*>(&out[((size_t)tok0 + t) * EE + e0]) = acc;
  }
}

extern "C" void kernel_launch(void* const* d_in, const int* in_sizes, int n_in,
                              void* d_out, int out_size, void* d_ws, size_t ws_size,
                              hipStream_t stream) {
  const float* x     = (const float*)d_in[0];
  const float* theta = (const float*)d_in[1];
  const float* W     = (const float*)d_in[2];
  const float* bias  = (const float*)d_in[3];
  float* out = (float*)d_out;
  float* y   = (float*)d_ws;

  qattn_mfma<<<256, 512, 0, stream>>>(x, theta, y);
  proj_kernel<<<256, 256, 0, stream>>>(y, W, bias, out);
}

// Round 11
// 19.550 us; speedup vs baseline: 4.8380x; 4.8380x over previous
//
#include <hip/hip_runtime.h>
#include <hip/hip_bf16.h>

#define SQ 1024
#define HH 16
#define DK 4
#define EE 64

using short8 = __attribute__((ext_vector_type(8))) short;
using f32x4  = __attribute__((ext_vector_type(4))) float;
using us4    = __attribute__((ext_vector_type(4))) unsigned short;
using us8    = __attribute__((ext_vector_type(8))) unsigned short;
using u32x4  = __attribute__((ext_vector_type(4))) unsigned;

static __device__ inline unsigned short f2bf(float f) {
  return __builtin_bit_cast(unsigned short, __float2bfloat16(f));
}

// Pack two f32 -> {lo: bf16(lo), hi: bf16(hi)} via byte-select (truncation;
// compensated by +log2(1+2^-8) in the QK MFMA C-operand, common-mode in
// num/den so it cancels in the softmax ratio).
static __device__ inline unsigned trunc_pk_bf16(float lo, float hi) {
  return __builtin_amdgcn_perm(__builtin_bit_cast(unsigned, hi),
                               __builtin_bit_cast(unsigned, lo),
                               0x07060302u);
}

// MFMA flash attention, token-split x2. grid = 64 bh x 4 quarters = 256
// blocks, 1024 threads (16 waves = 4 waves/SIMD; R10 counters showed the
// 8-wave version issue-starved at VALUBusy 59% from the MFMA->exp->MFMA
// chain). Waves w and w+8 own the SAME 32 queries; w does chunks 0..15,
// w+8 does 16..31. Partials (unnormalized num + den) add through LDS.
// Swapped QK^T (A = K-tokens), permuted token->row: mfma1 row i <- token
// 8*(i>>2)+(i&3), mfma2 +4, so QK D (col=lane&15=q, row=4h+r) equals the PV
// A-frag layout (k=8h+j); zero cross-lane ops. V ones-column at n=4 -> den.
__global__ __launch_bounds__(1024) void qattn_mfma(
    const float* __restrict__ x, const float* __restrict__ theta,
    float* __restrict__ y) {
  const int tid = threadIdx.x;
  const int quarter = blockIdx.x & 3;
  const int bh = blockIdx.x >> 2;
  const int hd = bh & (HH - 1);
  const int b = bh >> 4;

  // Carved shared: afrag 8K | vfrag 10.25K | qfrag 2K | zslot. The first
  // 16 KB (afrag+vfrag) is reused as the partial-accumulator exchange
  // buffer after the compute loop (guarded by __syncthreads).
  __shared__ __align__(16) unsigned char smem[20496];
  typedef unsigned short afrag_t[16][8];
  typedef unsigned short vfrag_t[4][5][8];
  afrag_t* afrag = reinterpret_cast<afrag_t*>(smem);                 // [32]
  vfrag_t* vfrag = reinterpret_cast<vfrag_t*>(smem + 8192);          // [32]
  unsigned short (*qfrag)[4] =
      reinterpret_cast<unsigned short (*)[4]>(smem + 18432);         // [256]
  unsigned short* zslot = reinterpret_cast<unsigned short*>(smem + 20480);
  f32x4* pex = reinterpret_cast<f32x4*>(smem);  // partial exchange, 16 KB

  const float4 th = *reinterpret_cast<const float4*>(theta);
  const float ct[4] = {__cosf(th.x), __cosf(th.y), __cosf(th.z), __cosf(th.w)};
  const float sc = 0.5f * 1.4426950408889634f;  // softmax scale * log2(e)
  const int q_lo = quarter * 256;

  if (tid < 8) zslot[tid] = 0;
  // ones column (1024 entries, 1/thread)
  vfrag[tid >> 5][(tid >> 3) & 3][4][tid & 7] = 0x3F80;

  // Stage proj = cos(x)*cos(theta) as bf16 fragments. 1 token/thread.
  const float* xb = x + ((size_t)b * SQ) * EE + hd * DK;
  {
    const int t = tid;
    const float4 v = *reinterpret_cast<const float4*>(xb + (size_t)t * EE);
    const float p[4] = {__cosf(v.x) * ct[0], __cosf(v.y) * ct[1],
                        __cosf(v.z) * ct[2], __cosf(v.w) * ct[3]};
    unsigned short pb[4], qb[4];
#pragma unroll
    for (int d = 0; d < 4; ++d) {
      pb[d] = f2bf(p[d]);
      qb[d] = f2bf(p[d] * sc);
    }
    const int c = t >> 5, tl = t & 31, hq = tl >> 3, j = tl & 7;
    *reinterpret_cast<us4*>(&afrag[c][4 * hq + (j & 3)][(j >= 4) ? 4 : 0]) =
        (us4){pb[0], pb[1], pb[2], pb[3]};
#pragma unroll
    for (int nn = 0; nn < 4; ++nn) vfrag[c][hq][nn][j] = pb[nn];
    const int ql = t - q_lo;
    if ((unsigned)ql < 256u)
      *reinterpret_cast<us4*>(&qfrag[ql][0]) = (us4){qb[0], qb[1], qb[2], qb[3]};
  }
  __syncthreads();

  const int lane = tid & 63;
  const int wid16 = tid >> 6;          // 0..15
  const int wid = wid16 & 7;           // query-group owner 0..7
  const int khalf = wid16 >> 3;        // 0: chunks 0-15, 1: chunks 16-31
  const int n = lane & 15, hg = lane >> 4;

  // Two Q fragments (B-operand): lanes<16 carry d=0..3, rest zero.
  short8 qf0 = {0, 0, 0, 0, 0, 0, 0, 0}, qf1 = qf0;
  {
    const unsigned short* qa =
        (lane < 16) ? &qfrag[wid * 32 + n][0] : &zslot[0];
    const unsigned short* qb2 =
        (lane < 16) ? &qfrag[wid * 32 + 16 + n][0] : &zslot[0];
    const us4 ta = *reinterpret_cast<const us4*>(qa);
    const us4 tb = *reinterpret_cast<const us4*>(qb2);
#pragma unroll
    for (int i = 0; i < 4; ++i) { qf0[i] = (short)ta[i]; qf1[i] = (short)tb[i]; }
  }

  const unsigned short* aptr = (lane < 16) ? &afrag[0][n][0] : &zslot[0];
  const int astep = (lane < 16) ? 128 : 0;  // ushorts per chunk
  const unsigned short* vptr = (n <= 4) ? &vfrag[0][hg][n][0] : &zslot[0];
  const int vstep = (n <= 4) ? 160 : 0;

  f32x4 acc0 = {0.f, 0.f, 0.f, 0.f}, acc1 = acc0;
  const float csh = 0.0056245491938781f;  // log2(1+2^-8) trunc compensation
  const f32x4 cc = {csh, csh, csh, csh};

  const int c0 = khalf * 16;
#pragma unroll 2
  for (int c = c0; c < c0 + 16; ++c) {
    const us8 av = *reinterpret_cast<const us8*>(aptr + c * astep);
    const short8 A1 = {(short)av[0], (short)av[1], (short)av[2], (short)av[3],
                       0, 0, 0, 0};
    const short8 A2 = {(short)av[4], (short)av[5], (short)av[6], (short)av[7],
                       0, 0, 0, 0};
    const f32x4 s1a = __builtin_amdgcn_mfma_f32_16x16x32_bf16(A1, qf0, cc, 0, 0, 0);
    const f32x4 s2a = __builtin_amdgcn_mfma_f32_16x16x32_bf16(A2, qf0, cc, 0, 0, 0);
    const f32x4 s1b = __builtin_amdgcn_mfma_f32_16x16x32_bf16(A1, qf1, cc, 0, 0, 0);
    const f32x4 s2b = __builtin_amdgcn_mfma_f32_16x16x32_bf16(A2, qf1, cc, 0, 0, 0);

    u32x4 p0, p1;
    p0[0] = trunc_pk_bf16(__builtin_amdgcn_exp2f(s1a[0]),
                          __builtin_amdgcn_exp2f(s1a[1]));
    p0[1] = trunc_pk_bf16(__builtin_amdgcn_exp2f(s1a[2]),
                          __builtin_amdgcn_exp2f(s1a[3]));
    p0[2] = trunc_pk_bf16(__builtin_amdgcn_exp2f(s2a[0]),
                          __builtin_amdgcn_exp2f(s2a[1]));
    p0[3] = trunc_pk_bf16(__builtin_amdgcn_exp2f(s2a[2]),
                          __builtin_amdgcn_exp2f(s2a[3]));
    p1[0] = trunc_pk_bf16(__builtin_amdgcn_exp2f(s1b[0]),
                          __builtin_amdgcn_exp2f(s1b[1]));
    p1[1] = trunc_pk_bf16(__builtin_amdgcn_exp2f(s1b[2]),
                          __builtin_amdgcn_exp2f(s1b[3]));
    p1[2] = trunc_pk_bf16(__builtin_amdgcn_exp2f(s2b[0]),
                          __builtin_amdgcn_exp2f(s2b[1]));
    p1[3] = trunc_pk_bf16(__builtin_amdgcn_exp2f(s2b[2]),
                          __builtin_amdgcn_exp2f(s2b[3]));
    const short8 PA0 = __builtin_bit_cast(short8, p0);
    const short8 PA1 = __builtin_bit_cast(short8, p1);

    const us8 vv = *reinterpret_cast<const us8*>(vptr + c * vstep);
    const short8 VB = __builtin_bit_cast(short8, vv);
    acc0 = __builtin_amdgcn_mfma_f32_16x16x32_bf16(PA0, VB, acc0, 0, 0, 0);
    acc1 = __builtin_amdgcn_mfma_f32_16x16x32_bf16(PA1, VB, acc1, 0, 0, 0);
  }

  // Token-split combine: waves 8-15 publish partials; waves 0-7 add.
  __syncthreads();  // everyone done reading afrag/vfrag
  if (khalf == 1) {
    const int p = wid * 64 + lane;
    pex[p * 2 + 0] = acc0;
    pex[p * 2 + 1] = acc1;
  }
  __syncthreads();
  if (khalf == 0) {
    const int p = wid * 64 + lane;
    acc0 += pex[p * 2 + 0];
    acc1 += pex[p * 2 + 1];

    // Epilogue: lane holds acc[r] = out[q = qbase+4*hg+r][col n]; n==4 = den.
#pragma unroll
    for (int half = 0; half < 2; ++half) {
      const f32x4 acc = half ? acc1 : acc0;
      const int qbase = q_lo + wid * 32 + half * 16;
#pragma unroll
      for (int r = 0; r < 4; ++r) {
        const float den = __shfl(acc[r], (lane & 48) | 4, 64);
        const float val = acc[r] * (1.0f / den);
        if (n < 4) {
          y[((size_t)(b * SQ + qbase + 4 * hg + r)) * EE + hd * DK + n] = val;
        }
      }
    }
  }
}

// Kernel 2: out[t,e] = bias[e] + sum_j y[t,j] * W[e,j]  (4096 x 64 x 64).
__global__ __launch_bounds__(256) void proj_kernel(
    const float* __restrict__ y, const float* __restrict__ W,
    const float* __restrict__ bias, float* __restrict__ out) {
  const int tid = threadIdx.x;
  __shared__ float Wt[EE][68];       // Wt[j][e] = W[e][j]
  __shared__ float yt[16][68];

  const float4* W4 = reinterpret_cast<const float4*>(W);
#pragma unroll
  for (int k = 0; k < 4; ++k) {
    const int i4 = tid + k * 256;
    const float4 w = W4[i4];
    const int e = i4 >> 4;
    const int j0 = (i4 & 15) * 4;
    Wt[j0 + 0][e] = w.x; Wt[j0 + 1][e] = w.y;
    Wt[j0 + 2][e] = w.z; Wt[j0 + 3][e] = w.w;
  }
  const size_t tok0 = (size_t)blockIdx.x * 16;
  {
    const float4 v = reinterpret_cast<const float4*>(y + tok0 * EE)[tid];
    *reinterpret_cast<float4*>(&yt[tid >> 4][(tid & 15) * 4]) = v;
  }
  __syncthreads();

  const int t = tid >> 4;            // token 0..15
  const int eg = tid & 15;           // 4-column group
  const int e0 = eg * 4;
  f32x4 acc = *reinterpret_cast<const f32x4*>(bias + e0);
#pragma unroll
  for (int jq = 0; jq < 16; ++jq) {
    const f32x4 yv = *reinterpret_cast<const f32x4*>(&yt[t][jq * 4]);
    const f32x4 w0 = *reinterpret_cast<const f32x4*>(&Wt[jq * 4 + 0][e0]);
    const f32x4 w1 = *reinterpret_cast<const f32x4*>(&Wt[jq * 4 + 1][e0]);
    const f32x4 w2 = *reinterpret_cast<const f32x4*>(&Wt[jq * 4 + 2][e0]);
    const f32x4 w3 = *reinterpret_cast<const f32x4*>(&Wt[jq * 4 + 3][e0]);
    acc += yv[0] * w0 + yv[1] * w1 + yv[2] * w2 + yv[3] * w3;
  }
  *reinterpret_cast<f32x4*>(&out[((size_t)tok0 + t) * EE + e0]) = acc;
}

extern "C" void kernel_launch(void* const* d_in, const int* in_sizes, int n_in,
                              void* d_out, int out_size, void* d_ws, size_t ws_size,
                              hipStream_t stream) {
  const float* x     = (const float*)d_in[0];
  const float* theta = (const float*)d_in[1];
  const float* W     = (const float*)d_in[2];
  const float* bias  = (const float*)d_in[3];
  float* out = (float*)d_out;
  float* y   = (float*)d_ws;  // [B,S,E] fp32 = 1 MB attention output

  qattn_mfma<<<256, 1024, 0, stream>>>(x, theta, y);
  proj_kernel<<<256, 256, 0, stream>>>(y, W, bias, out);
}